// Round 1
// baseline (229.375 us; speedup 1.0000x reference)
//
#include <hip/hip_runtime.h>
#include <hip/hip_bf16.h>
#include <hip/hip_fp16.h>

// Problem: CausalSelfAttention  B=4, S=2048, D_IN=D_OUT=1024 (single 1024-wide head)
//   q = x@Wq^T ; k = x@Wk^T ; v = x@Wv^T
//   S = q@k^T (causal mask -inf, then *1/32), P = softmax(S), out = P@v  (fp32 out)
//
// Plan: bf16 MFMA for all three GEMM stages (threshold 4.375e-2 allows it).
// All GEMMs arranged NT (C = A * B^T, A,B row-major over K) -> one template kernel.

using bf16 = __hip_bfloat16;
typedef __bf16 bf16x8 __attribute__((ext_vector_type(8)));
typedef float f32x4 __attribute__((ext_vector_type(4)));

__device__ __forceinline__ void load_lds_16B(const void* g, void* l) {
  __builtin_amdgcn_global_load_lds(
      (const __attribute__((address_space(1))) unsigned int*)g,
      (__attribute__((address_space(3))) unsigned int*)l, 16, 0, 0);
}

// ---------------------------------------------------------------------------
// NT GEMM: C[M,N] = A[M,K] * B[N,K]^T   (A,B bf16 row-major, C fp32 or bf16)
// 128x128 tile, BK=32, 256 threads = 4 waves in 2x2, each wave 64x64 (4x4 frags)
// m97 structure: global_load_lds width-16 staging, 2-barrier K loop.
// ---------------------------------------------------------------------------
template <bool OUT_BF16, bool CSKIP, bool KLIM>
__global__ __launch_bounds__(256) void gemm_nt(
    const bf16* __restrict__ A, const bf16* __restrict__ Bm, void* __restrict__ Cv,
    int M, int N, int K, long sAz, long sBz, long sCzBytes) {
  const int tn = blockIdx.x, tm = blockIdx.y, z = blockIdx.z;
  if (CSKIP && tn > tm) return;  // fully-masked score tile (BM==BN)
  A += (long)z * sAz;
  Bm += (long)z * sBz;
  char* C = (char*)Cv + (long)z * sCzBytes;
  int kEnd = K;
  if (KLIM) {  // causal PV: P[q,k]==0 for k > q
    int lim = tm * 128 + 128;
    kEnd = lim < K ? lim : K;
  }

  __shared__ bf16 As[128 * 32];
  __shared__ bf16 Bs[128 * 32];

  const int tid = threadIdx.x;
  const int lane = tid & 63, wv = tid >> 6;
  const int wr = wv >> 1, wc = wv & 1;

  // staging: thread covers tile elems [tid*8, tid*8+7]; issue1 = +2048 elems (row+64)
  const int r0 = tid >> 2;            // (tid*8)/32
  const int c0 = (tid & 3) * 8;       // (tid*8)%32
  const bf16* gA = A + (long)(tm * 128 + r0) * K + c0;
  const bf16* gB = Bm + (long)(tn * 128 + r0) * K + c0;
  char* ldsA0 = (char*)As + wv * 1024;  // wave-uniform base, HW adds lane*16
  char* ldsB0 = (char*)Bs + wv * 1024;

  f32x4 acc[4][4] = {};

  const int fr = lane & 15;
  const int fk = (lane >> 4) * 8;
  const bf16* aF = As + (wr * 64 + fr) * 32 + fk;
  const bf16* bF = Bs + (wc * 64 + fr) * 32 + fk;

  for (int k0 = 0; k0 < kEnd; k0 += 32) {
    load_lds_16B(gA, ldsA0);
    load_lds_16B(gA + 64 * (long)K, ldsA0 + 4096);
    load_lds_16B(gB, ldsB0);
    load_lds_16B(gB + 64 * (long)K, ldsB0 + 4096);
    gA += 32;
    gB += 32;
    __syncthreads();  // compiler drains vmcnt before barrier -> LDS ready

    bf16x8 af[4], bg[4];
#pragma unroll
    for (int m = 0; m < 4; m++) af[m] = *(const bf16x8*)(aF + m * 16 * 32);
#pragma unroll
    for (int n = 0; n < 4; n++) bg[n] = *(const bf16x8*)(bF + n * 16 * 32);
#pragma unroll
    for (int m = 0; m < 4; m++)
#pragma unroll
      for (int n = 0; n < 4; n++)
        acc[m][n] = __builtin_amdgcn_mfma_f32_16x16x32_bf16(af[m], bg[n], acc[m][n], 0, 0, 0);
    __syncthreads();  // all waves done reading before next stage overwrites
  }

  // epilogue: D row = (lane>>4)*4 + reg, col = lane&15  (m89-verified layout)
  const int cr0 = tm * 128 + wr * 64 + (lane >> 4) * 4;
  const int cc0 = tn * 128 + wc * 64 + (lane & 15);
#pragma unroll
  for (int m = 0; m < 4; m++)
#pragma unroll
    for (int n = 0; n < 4; n++)
#pragma unroll
      for (int j = 0; j < 4; j++) {
        long row = cr0 + m * 16 + j;
        long col = cc0 + n * 16;
        if (OUT_BF16)
          ((bf16*)C)[row * (long)N + col] = __float2bfloat16(acc[m][n][j]);
        else
          ((float*)C)[row * (long)N + col] = acc[m][n][j];
      }
}

// ---------------------------------------------------------------------------
// fp32 -> bf16 convert, 4 elems/thread
// ---------------------------------------------------------------------------
__global__ __launch_bounds__(256) void cvt4(const float* __restrict__ src,
                                            bf16* __restrict__ dst, int n4) {
  int i = blockIdx.x * 256 + threadIdx.x;
  if (i >= n4) return;
  float4 f = ((const float4*)src)[i];
  union {
    bf16 b[4];
    uint2 u;
  } o;
  o.b[0] = __float2bfloat16(f.x);
  o.b[1] = __float2bfloat16(f.y);
  o.b[2] = __float2bfloat16(f.z);
  o.b[3] = __float2bfloat16(f.w);
  ((uint2*)dst)[i] = o.u;
}

// ---------------------------------------------------------------------------
// causal row softmax: P[b,i,j] = softmax_j<=i( S[b,i,j] / 32 ), 0 for j>i (bf16)
// one 256-thread block per row (row length <= 2048 -> 8 elems/thread)
// ---------------------------------------------------------------------------
__global__ __launch_bounds__(256) void softmax_causal(const float* __restrict__ Sc,
                                                      bf16* __restrict__ P) {
  const int i = blockIdx.x;
  const int b = blockIdx.y;
  const long base = ((long)b * 2048 + i) * 2048;
  const float* row = Sc + base;
  bf16* prow = P + base;
  const int tid = threadIdx.x;
  const int lane = tid & 63, wv = tid >> 6;
  const int len = i + 1;

  float v[8];
#pragma unroll
  for (int u = 0; u < 8; u++) {
    int j = tid + u * 256;
    v[u] = (j < len) ? row[j] : -3.3e38f;
  }
  float m = v[0];
#pragma unroll
  for (int u = 1; u < 8; u++) m = fmaxf(m, v[u]);
  for (int o = 32; o; o >>= 1) m = fmaxf(m, __shfl_xor(m, o));
  __shared__ float redm[4];
  __shared__ float reds[4];
  if (lane == 0) redm[wv] = m;
  __syncthreads();
  m = fmaxf(fmaxf(redm[0], redm[1]), fmaxf(redm[2], redm[3]));

  const float scale = 0.03125f;  // 1/sqrt(1024)
  float e[8];
  float s = 0.f;
#pragma unroll
  for (int u = 0; u < 8; u++) {
    int j = tid + u * 256;
    float t = (j < len) ? __expf((v[u] - m) * scale) : 0.f;
    e[u] = t;
    s += t;
  }
  for (int o = 32; o; o >>= 1) s += __shfl_xor(s, o);
  if (lane == 0) reds[wv] = s;
  __syncthreads();
  s = reds[0] + reds[1] + reds[2] + reds[3];
  float inv = 1.0f / s;
#pragma unroll
  for (int u = 0; u < 8; u++) {
    int j = tid + u * 256;
    prow[j] = __float2bfloat16(e[u] * inv);  // writes 0 for masked j>i
  }
}

// ---------------------------------------------------------------------------
// V[b,s,d] -> Vt[b,d,s] (bf16), 32x32 LDS tiles
// ---------------------------------------------------------------------------
__global__ __launch_bounds__(256) void transposeV(const bf16* __restrict__ V,
                                                  bf16* __restrict__ Vt) {
  __shared__ bf16 t[32][33];
  const int b = blockIdx.z;
  const int s0 = blockIdx.x << 5;
  const int d0 = blockIdx.y << 5;
  const bf16* Vb = V + (long)b * 2048 * 1024;
  bf16* Vtb = Vt + (long)b * 1024 * 2048;
  const int lx = threadIdx.x & 31, ly = threadIdx.x >> 5;
#pragma unroll
  for (int r = 0; r < 32; r += 8)
    t[r + ly][lx] = Vb[(long)(s0 + r + ly) * 1024 + d0 + lx];
  __syncthreads();
#pragma unroll
  for (int r = 0; r < 32; r += 8)
    Vtb[(long)(d0 + r + ly) * 2048 + s0 + lx] = t[lx][r + ly];
}

// ---------------------------------------------------------------------------
// Workspace layout (160 MB):
//   [0,16M)   Q bf16        [16M,32M)  K bf16       [32M,48M)  V bf16
//   [48M,64M) Vt bf16       [64M,96M)  P bf16
//   [96M,160M) scores fp32  -- aliases xb@96M (16M) + Wb@112M (6M), which are
//                              dead by the time the scores GEMM writes here.
// ---------------------------------------------------------------------------
extern "C" void kernel_launch(void* const* d_in, const int* in_sizes, int n_in,
                              void* d_out, int out_size, void* d_ws, size_t ws_size,
                              hipStream_t stream) {
  const float* x = (const float*)d_in[0];
  const float* Wq = (const float*)d_in[1];
  const float* Wk = (const float*)d_in[2];
  const float* Wv = (const float*)d_in[3];

  const long MBy = 1 << 20;
  char* ws = (char*)d_ws;
  bf16* Q = (bf16*)(ws);
  bf16* Kb = (bf16*)(ws + 16 * MBy);
  bf16* V = (bf16*)(ws + 32 * MBy);
  bf16* Vt = (bf16*)(ws + 48 * MBy);
  bf16* P = (bf16*)(ws + 64 * MBy);
  float* Sc = (float*)(ws + 96 * MBy);
  bf16* xb = (bf16*)(ws + 96 * MBy);
  bf16* Wb = (bf16*)(ws + 112 * MBy);

  // 1) convert inputs to bf16
  cvt4<<<8192, 256, 0, stream>>>(x, xb, 2097152);        // 4*2048*1024 / 4
  cvt4<<<1024, 256, 0, stream>>>(Wq, Wb, 262144);        // 1024*1024 / 4
  cvt4<<<1024, 256, 0, stream>>>(Wk, Wb + 1048576, 262144);
  cvt4<<<1024, 256, 0, stream>>>(Wv, Wb + 2097152, 262144);

  // 2) QKV projection: [8192,1024] = xb[8192,1024] * W[1024,1024]^T, z over {q,k,v}
  gemm_nt<true, false, false><<<dim3(8, 64, 3), 256, 0, stream>>>(
      xb, Wb, Q, 8192, 1024, 1024, 0L, 1048576L, 16 * MBy);

  // 3) scores: per batch, S[2048,2048] = Q * K^T (raw, fp32); skip masked tiles
  gemm_nt<false, true, false><<<dim3(16, 16, 4), 256, 0, stream>>>(
      Q, Kb, Sc, 2048, 2048, 1024, 2048L * 1024, 2048L * 1024, 2048L * 2048 * 4);

  // 4) causal softmax (applies 1/32 scale), P bf16 with zeros above diagonal
  softmax_causal<<<dim3(2048, 4), 256, 0, stream>>>(Sc, P);

  // 5) V transpose for NT PV GEMM
  transposeV<<<dim3(64, 32, 4), 256, 0, stream>>>(V, Vt);

  // 6) out[2048,1024] = P[2048,2048] * Vt[1024,2048]^T, causal K-limit
  gemm_nt<false, false, true><<<dim3(8, 16, 4), 256, 0, stream>>>(
      P, Vt, d_out, 2048, 1024, 2048, 2048L * 2048, 1024L * 2048, 2048L * 1024 * 4);
}

// Round 2
// 182.326 us; speedup vs baseline: 1.2580x; 1.2580x over previous
//
#include <hip/hip_runtime.h>
#include <hip/hip_bf16.h>
#include <hip/hip_fp16.h>

// CausalSelfAttention  B=4, S=2048, D=1024 (single wide head), fp32 in/out.
// bf16 MFMA for all GEMM stages. All GEMMs NT: C[M,N] = A[M,K] * B[N,K]^T.
//
// R2: deep-pipelined GEMM template — 512 thr (8 waves 2x4), BK=32, 4 LDS
// buffers, counted vmcnt (stage 3 tiles ahead, never drain to 0 mid-loop),
// raw s_barrier (1 per K-tile), XOR-swizzled LDS (both sides: pre-swizzled
// global source for global_load_lds + swizzled ds_read_b128), setprio around
// the MFMA cluster. ~32 MFMA per barrier per wave.

using bf16 = __hip_bfloat16;
typedef __bf16 bf16x8 __attribute__((ext_vector_type(8)));
typedef float f32x4 __attribute__((ext_vector_type(4)));

__device__ __forceinline__ void load_lds_16B(const void* g, void* l) {
  __builtin_amdgcn_global_load_lds(
      (const __attribute__((address_space(1))) unsigned int*)g,
      (__attribute__((address_space(3))) unsigned int*)l, 16, 0, 0);
}

template <int N>
__device__ __forceinline__ void waitcnt_vm() {
  if constexpr (N == 8) asm volatile("s_waitcnt vmcnt(8)" ::: "memory");
  else if constexpr (N == 6) asm volatile("s_waitcnt vmcnt(6)" ::: "memory");
  else if constexpr (N == 4) asm volatile("s_waitcnt vmcnt(4)" ::: "memory");
  else if constexpr (N == 3) asm volatile("s_waitcnt vmcnt(3)" ::: "memory");
  else asm volatile("s_waitcnt vmcnt(0)" ::: "memory");
}

// swizzle: XOR bits[6:4] of the byte offset with bits[9:7] (disjoint -> involution).
// [R][32]bf16 rows = 64B: spreads 8 consecutive rows across 8 16B slots -> 2-way
// conflict (free, m136) instead of 8-way.
__device__ __forceinline__ int swz(int o) { return o ^ (((o >> 7) & 7) << 4); }

// ---------------------------------------------------------------------------
// NT GEMM, BN=256 fixed, BM = M_REP*32 (M_REP=8 -> 256, M_REP=4 -> 128).
// 512 threads = 8 waves as 2(M) x 4(N); per-wave tile (M_REP*16) x 64.
// ---------------------------------------------------------------------------
template <int M_REP, bool OUT_BF16, bool CSKIP, bool KLIM>
__global__ __launch_bounds__(512, 2) void gemm_pipe(
    const bf16* __restrict__ A, const bf16* __restrict__ Bm, void* __restrict__ Cv,
    int M, int N, int K, long sAz, long sBz, long sCzBytes) {
  constexpr int BM = M_REP * 32;
  constexpr int BN = 256;
  constexpr int ABYT = BM * 64;   // A-tile bytes per buffer (BK=32 bf16)
  constexpr int BBYT = BN * 64;   // B-tile bytes per buffer
  constexpr int NCALL = (ABYT + BBYT) / 8192;  // global_load_lds per thread per tile

  const int tn = blockIdx.x, tm = blockIdx.y, z = blockIdx.z;
  if (CSKIP && tn * BN >= tm * BM + BM) return;  // fully-masked score tile
  A += (long)z * sAz;
  Bm += (long)z * sBz;
  char* C = (char*)Cv + (long)z * sCzBytes;

  int kEnd = K;
  if (KLIM) kEnd = min(tm * BM + BM, K);  // causal PV: P[q,k]==0 for k>q
  const int nt = kEnd >> 5;

  __shared__ char sm[4 * (ABYT + BBYT)];  // 4 buffers: [4][A] then [4][B]

  const int tid = threadIdx.x;
  const int lane = tid & 63, wv = tid >> 6;
  const int wr = wv >> 2, wc = wv & 3;

  // --- staging setup: per-call pre-swizzled global source + linear LDS dest ---
  const char* srcp[NCALL];
  int ldsbase[NCALL];
  int bufstride[NCALL];
#pragma unroll
  for (int c = 0; c < NCALL; c++) {
    int oall = c * 8192 + tid * 16;       // linear offset over [A-tile | B-tile]
    int oc = c * 8192 + wv * 1024;        // wave-uniform LDS part
    bool isB = oall >= ABYT;              // 8192-granular: uniform per call
    int toff = isB ? (oall - ABYT) : oall;
    int os = swz(toff);                   // LDS linear dest <- swizzled source
    int row = os >> 6, colb = os & 63;
    const bf16* rowp = isB ? (Bm + (long)(tn * BN + row) * K)
                           : (A + (long)(tm * BM + row) * K);
    srcp[c] = (const char*)rowp + colb;
    ldsbase[c] = isB ? (4 * ABYT + (oc - ABYT)) : oc;
    bufstride[c] = isB ? BBYT : ABYT;
  }
  auto stage = [&](int tt) {
#pragma unroll
    for (int c = 0; c < NCALL; c++)
      load_lds_16B(srcp[c] + (long)tt * 64, sm + ldsbase[c] + (tt & 3) * bufstride[c]);
  };

  // --- fragment LDS offsets (swizzled) ---
  int aoff[M_REP], boff[4];
#pragma unroll
  for (int m = 0; m < M_REP; m++) {
    int row = wr * (M_REP * 16) + m * 16 + (lane & 15);
    aoff[m] = swz(row * 64 + (lane >> 4) * 16);
  }
#pragma unroll
  for (int n = 0; n < 4; n++) {
    int row = wc * 64 + n * 16 + (lane & 15);
    boff[n] = swz(row * 64 + (lane >> 4) * 16) + 4 * ABYT;
  }

  f32x4 acc[M_REP][4] = {};

  // prologue: stage tiles 0..2
  if (nt > 0) stage(0);
  if (nt > 1) stage(1);
  if (nt > 2) stage(2);

  for (int t = 0; t < nt; t++) {
    // counted wait: tile t ready; up to 2 newer tiles stay in flight
    if (t + 3 <= nt) waitcnt_vm<2 * NCALL>();
    else if (t + 2 == nt) waitcnt_vm<NCALL>();
    else waitcnt_vm<0>();
    __builtin_amdgcn_s_barrier();

    const int buf = t & 3;
    bf16x8 bfr[4], afr[M_REP];
#pragma unroll
    for (int n = 0; n < 4; n++)
      bfr[n] = *(const bf16x8*)(sm + boff[n] + buf * BBYT);
#pragma unroll
    for (int m = 0; m < M_REP; m++)
      afr[m] = *(const bf16x8*)(sm + aoff[m] + buf * ABYT);

    if (t + 3 < nt) stage(t + 3);  // into buf[(t+3)&3] = retired buf[(t-1)&3]

    __builtin_amdgcn_s_setprio(1);
#pragma unroll
    for (int m = 0; m < M_REP; m++)
#pragma unroll
      for (int n = 0; n < 4; n++)
        acc[m][n] = __builtin_amdgcn_mfma_f32_16x16x32_bf16(afr[m], bfr[n], acc[m][n], 0, 0, 0);
    __builtin_amdgcn_s_setprio(0);
  }

  // epilogue: D row = (lane>>4)*4 + j, col = lane&15 (m89-verified)
  const int cr0 = tm * BM + wr * (M_REP * 16) + (lane >> 4) * 4;
  const int cc0 = tn * BN + wc * 64 + (lane & 15);
#pragma unroll
  for (int m = 0; m < M_REP; m++)
#pragma unroll
    for (int n = 0; n < 4; n++)
#pragma unroll
      for (int j = 0; j < 4; j++) {
        long row = cr0 + m * 16 + j;
        long col = cc0 + n * 16;
        if (OUT_BF16)
          ((bf16*)C)[row * (long)N + col] = __float2bfloat16(acc[m][n][j]);
        else
          ((float*)C)[row * (long)N + col] = acc[m][n][j];
      }
}

// ---------------------------------------------------------------------------
// fp32 -> bf16 convert, 4 elems/thread
// ---------------------------------------------------------------------------
__global__ __launch_bounds__(256) void cvt4(const float* __restrict__ src,
                                            bf16* __restrict__ dst, int n4) {
  int i = blockIdx.x * 256 + threadIdx.x;
  if (i >= n4) return;
  float4 f = ((const float4*)src)[i];
  union {
    bf16 b[4];
    uint2 u;
  } o;
  o.b[0] = __float2bfloat16(f.x);
  o.b[1] = __float2bfloat16(f.y);
  o.b[2] = __float2bfloat16(f.z);
  o.b[3] = __float2bfloat16(f.w);
  ((uint2*)dst)[i] = o.u;
}

// ---------------------------------------------------------------------------
// causal row softmax: P[b,i,j] = softmax_j<=i( S[b,i,j] / 32 ), 0 for j>i (bf16)
// ---------------------------------------------------------------------------
__global__ __launch_bounds__(256) void softmax_causal(const float* __restrict__ Sc,
                                                      bf16* __restrict__ P) {
  const int i = blockIdx.x;
  const int b = blockIdx.y;
  const long base = ((long)b * 2048 + i) * 2048;
  const float* row = Sc + base;
  bf16* prow = P + base;
  const int tid = threadIdx.x;
  const int lane = tid & 63, wv = tid >> 6;
  const int len = i + 1;

  float v[8];
#pragma unroll
  for (int u = 0; u < 8; u++) {
    int j = tid + u * 256;
    v[u] = (j < len) ? row[j] : -3.3e38f;
  }
  float m = v[0];
#pragma unroll
  for (int u = 1; u < 8; u++) m = fmaxf(m, v[u]);
  for (int o = 32; o; o >>= 1) m = fmaxf(m, __shfl_xor(m, o));
  __shared__ float redm[4];
  __shared__ float reds[4];
  if (lane == 0) redm[wv] = m;
  __syncthreads();
  m = fmaxf(fmaxf(redm[0], redm[1]), fmaxf(redm[2], redm[3]));

  const float scale = 0.03125f;  // 1/sqrt(1024)
  float e[8];
  float s = 0.f;
#pragma unroll
  for (int u = 0; u < 8; u++) {
    int j = tid + u * 256;
    float t = (j < len) ? __expf((v[u] - m) * scale) : 0.f;
    e[u] = t;
    s += t;
  }
  for (int o = 32; o; o >>= 1) s += __shfl_xor(s, o);
  if (lane == 0) reds[wv] = s;
  __syncthreads();
  s = reds[0] + reds[1] + reds[2] + reds[3];
  float inv = 1.0f / s;
#pragma unroll
  for (int u = 0; u < 8; u++) {
    int j = tid + u * 256;
    prow[j] = __float2bfloat16(e[u] * inv);
  }
}

// ---------------------------------------------------------------------------
// V[b,s,d] -> Vt[b,d,s] (bf16), 32x32 LDS tiles
// ---------------------------------------------------------------------------
__global__ __launch_bounds__(256) void transposeV(const bf16* __restrict__ V,
                                                  bf16* __restrict__ Vt) {
  __shared__ bf16 t[32][33];
  const int b = blockIdx.z;
  const int s0 = blockIdx.x << 5;
  const int d0 = blockIdx.y << 5;
  const bf16* Vb = V + (long)b * 2048 * 1024;
  bf16* Vtb = Vt + (long)b * 1024 * 2048;
  const int lx = threadIdx.x & 31, ly = threadIdx.x >> 5;
#pragma unroll
  for (int r = 0; r < 32; r += 8)
    t[r + ly][lx] = Vb[(long)(s0 + r + ly) * 1024 + d0 + lx];
  __syncthreads();
#pragma unroll
  for (int r = 0; r < 32; r += 8)
    Vtb[(long)(d0 + r + ly) * 2048 + s0 + lx] = t[lx][r + ly];
}

// ---------------------------------------------------------------------------
// Workspace layout (160 MB):
//   [0,16M)   Q bf16        [16M,32M)  K bf16       [32M,48M)  V bf16
//   [48M,64M) Vt bf16       [64M,96M)  P bf16
//   [96M,160M) scores fp32  -- aliases xb@96M (16M) + Wb@112M (6M), dead by
//                              the time the scores GEMM writes here.
// ---------------------------------------------------------------------------
extern "C" void kernel_launch(void* const* d_in, const int* in_sizes, int n_in,
                              void* d_out, int out_size, void* d_ws, size_t ws_size,
                              hipStream_t stream) {
  const float* x = (const float*)d_in[0];
  const float* Wq = (const float*)d_in[1];
  const float* Wk = (const float*)d_in[2];
  const float* Wv = (const float*)d_in[3];

  const long MBy = 1 << 20;
  char* ws = (char*)d_ws;
  bf16* Q = (bf16*)(ws);
  bf16* Kb = (bf16*)(ws + 16 * MBy);
  bf16* V = (bf16*)(ws + 32 * MBy);
  bf16* Vt = (bf16*)(ws + 48 * MBy);
  bf16* P = (bf16*)(ws + 64 * MBy);
  float* Sc = (float*)(ws + 96 * MBy);
  bf16* xb = (bf16*)(ws + 96 * MBy);
  bf16* Wb = (bf16*)(ws + 112 * MBy);

  // 1) convert inputs to bf16
  cvt4<<<8192, 256, 0, stream>>>(x, xb, 2097152);
  cvt4<<<1024, 256, 0, stream>>>(Wq, Wb, 262144);
  cvt4<<<1024, 256, 0, stream>>>(Wk, Wb + 1048576, 262144);
  cvt4<<<1024, 256, 0, stream>>>(Wv, Wb + 2097152, 262144);

  // 2) QKV projection: [8192,1024] = xb * W^T, z over {q,k,v}. BM=128 -> 768
  //    blocks = exactly 3 occupancy rounds at 1 block/CU.
  gemm_pipe<4, true, false, false><<<dim3(4, 64, 3), 512, 0, stream>>>(
      xb, Wb, Q, 8192, 1024, 1024, 0L, 1048576L, 16 * MBy);

  // 3) scores: per batch S[2048,2048] = Q*K^T (fp32); skip masked tiles. 256^2.
  gemm_pipe<8, false, true, false><<<dim3(8, 8, 4), 512, 0, stream>>>(
      Q, Kb, Sc, 2048, 2048, 1024, 2048L * 1024, 2048L * 1024, 2048L * 2048 * 4);

  // 4) causal softmax (applies 1/32 scale), P bf16 with zeros above diagonal
  softmax_causal<<<dim3(2048, 4), 256, 0, stream>>>(Sc, P);

  // 5) V transpose for NT PV GEMM
  transposeV<<<dim3(64, 32, 4), 256, 0, stream>>>(V, Vt);

  // 6) out[2048,1024] = P * Vt^T, causal K-limit. BM=128 -> 256 blocks = 1
  //    round; max-K straggler block K=2048 is half the 256^2 cost.
  gemm_pipe<4, false, false, true><<<dim3(4, 16, 4), 512, 0, stream>>>(
      P, Vt, d_out, 2048, 1024, 2048, 2048L * 2048, 1024L * 2048, 2048L * 1024 * 4);
}

// Round 3
// 169.421 us; speedup vs baseline: 1.3539x; 1.0762x over previous
//
#include <hip/hip_runtime.h>
#include <hip/hip_bf16.h>

// CausalSelfAttention  B=4, S=2048, D=1024 (single wide head), fp32 in/out.
// R3: m201-style 8-phase 256-wide-tile GEMM template, BK=64, kc-split
// half-tile staging stream, counted vmcnt(6/5) at phases 4&8, 2-deep LDS dbuf,
// XOR swizzle (verified 0-conflict in R2), setprio around MFMA clusters.

using bf16 = __hip_bfloat16;
typedef __bf16 bf16x8 __attribute__((ext_vector_type(8)));
typedef float f32x4 __attribute__((ext_vector_type(4)));

__device__ __forceinline__ void load_lds_16B(const void* g, void* l) {
  __builtin_amdgcn_global_load_lds(
      (const __attribute__((address_space(1))) unsigned int*)g,
      (__attribute__((address_space(3))) unsigned int*)l, 16, 0, 0);
}

template <int N>
__device__ __forceinline__ void waitcnt_vm() {
  if constexpr (N == 6) asm volatile("s_waitcnt vmcnt(6)" ::: "memory");
  else if constexpr (N == 5) asm volatile("s_waitcnt vmcnt(5)" ::: "memory");
  else asm volatile("s_waitcnt vmcnt(0)" ::: "memory");
}

// XOR bits[6:4] by bits[9:7] (disjoint -> involution). On [R][32]bf16 chunks
// (64B rows) this made 16-row ds_read_b128 frag reads conflict-free (R2: 0).
__device__ __forceinline__ int swz(int o) { return o ^ (((o >> 7) & 7) << 4); }

// ---------------------------------------------------------------------------
// NT GEMM: C[M,N] = A[M,K]*B[N,K]^T. BN=256, BM=M_REP*32. 512 thr = 8 waves
// (2M x 4N), wave tile (M_REP*16) x 64. BK=64 split in two kc-chunks of 32.
// LDS per K-tile buffer: A[2][BM][32], B[2][256][32]; 2 buffers.
// 8 phases per 2 K-tiles; staging stream = 1 half-chunk per phase:
//   P1:Ak1(tb) P2:Bk0(ta+2) P3:Ak0(ta+2) P4:Bk1(ta+2)
//   P5:Ak1(ta+2) P6:Bk0(tb+2) P7:Ak0(tb+2) P8:Bk1(tb+2)
// Each stage overwrites a slot whose consumers finished >=1 phase earlier.
// vmcnt(VM_LEAVE) at P4/P8 completes everything except the last 3 units.
// ---------------------------------------------------------------------------
template <int M_REP, bool OUT_BF16, bool CSKIP, bool KLIM>
__global__ __launch_bounds__(512, 2) void gemm8p(
    const bf16* __restrict__ A, const bf16* __restrict__ Bm, void* __restrict__ Cv,
    int M, int N, int K, long sAz, long sBz, long sCzBytes) {
  constexpr int BM = M_REP * 32, BN = 256;
  constexpr int MH2 = M_REP / 2;
  constexpr int AKC = BM * 64;   // bytes per A kc-chunk [BM][32]bf16
  constexpr int BKC = BN * 64;   // bytes per B kc-chunk
  constexpr int DBSTR = 2 * AKC + 2 * BKC;
  constexpr int ACALLS = AKC / 8192;  // gload_lds calls/thread per A-chunk
  constexpr int VM_LEAVE = ACALLS + 4;  // last 3 units = B + A + B

  const int tn = blockIdx.x, tm = blockIdx.y, z = blockIdx.z;
  if (CSKIP && tn > tm) return;  // fully-masked score tile (BM==BN)
  A += (long)z * sAz;
  Bm += (long)z * sBz;
  char* C = (char*)Cv + (long)z * sCzBytes;

  int kEnd = K;
  if (KLIM) kEnd = min(tm * BM + BM, K);  // causal PV: P[q,k]==0 for k>q
  const int nt = kEnd >> 6;  // K-tiles of 64 (always even here)
  const int NI = nt >> 1;

  __shared__ __align__(128) char sm[2 * DBSTR];
  const int tid = threadIdx.x, lane = tid & 63, wv = tid >> 6;
  const int wr = wv >> 2, wc = wv & 3;
  const int ldsw = wv * 1024;

  // staging: linear LDS dest, pre-swizzled global source (both-sides rule)
  const char* srcA[ACALLS];
  const char* srcB[2];
#pragma unroll
  for (int c = 0; c < ACALLS; c++) {
    int os = swz(c * 8192 + tid * 16);
    srcA[c] = (const char*)(A + ((long)tm * BM + (os >> 6)) * K) + (os & 63);
  }
#pragma unroll
  for (int c = 0; c < 2; c++) {
    int os = swz(c * 8192 + tid * 16);
    srcB[c] = (const char*)(Bm + ((long)tn * BN + (os >> 6)) * K) + (os & 63);
  }
  auto stageA = [&](int t, int kc) {
#pragma unroll
    for (int c = 0; c < ACALLS; c++)
      load_lds_16B(srcA[c] + (long)t * 128 + kc * 64,
                   sm + (t & 1) * DBSTR + kc * AKC + c * 8192 + ldsw);
  };
  auto stageB = [&](int t, int kc) {
#pragma unroll
    for (int c = 0; c < 2; c++)
      load_lds_16B(srcB[c] + (long)t * 128 + kc * 64,
                   sm + (t & 1) * DBSTR + 2 * AKC + kc * BKC + c * 8192 + ldsw);
  };

  // fragment LDS offsets (swizzled), within a kc-chunk
  int aoff[M_REP], boff[4];
#pragma unroll
  for (int m = 0; m < M_REP; m++)
    aoff[m] = swz((wr * (M_REP * 16) + m * 16 + (lane & 15)) * 64 + (lane >> 4) * 16);
#pragma unroll
  for (int n = 0; n < 4; n++)
    boff[n] = 2 * AKC + swz((wc * 64 + n * 16 + (lane & 15)) * 64 + (lane >> 4) * 16);

  f32x4 acc[M_REP][4] = {};
  bf16x8 bfr[2][4];
  bf16x8 afrA[MH2], afrB[MH2];

#define LDB(DBUF, KC)                                                          \
  _Pragma("unroll") for (int n = 0; n < 4; n++)                                \
      bfr[KC][n] = *(const bf16x8*)(sm + (DBUF)*DBSTR + (KC)*BKC + boff[n]);
#define LDA(DBUF, KC, MH, DST)                                                 \
  _Pragma("unroll") for (int m = 0; m < MH2; m++)                              \
      DST[m] = *(const bf16x8*)(sm + (DBUF)*DBSTR + (KC)*AKC + aoff[(MH)*MH2 + m]);
#define MFMAS(KC, MH, AFR)                                                     \
  __builtin_amdgcn_s_setprio(1);                                               \
  _Pragma("unroll") for (int m = 0; m < MH2; m++)                              \
      _Pragma("unroll") for (int n = 0; n < 4; n++)                            \
          acc[(MH)*MH2 + m][n] = __builtin_amdgcn_mfma_f32_16x16x32_bf16(      \
              AFR[m], bfr[KC][n], acc[(MH)*MH2 + m][n], 0, 0, 0);              \
  __builtin_amdgcn_s_setprio(0);
#define BAR1()                                                                 \
  __builtin_amdgcn_s_barrier();                                                \
  asm volatile("s_waitcnt lgkmcnt(0)" ::: "memory");                           \
  __builtin_amdgcn_sched_barrier(0);
#define BAR2() __builtin_amdgcn_s_barrier();

  // prologue: tile0 fully + tile1 minus Ak1 (completed by first P1)
  stageB(0, 0); stageA(0, 0); stageB(0, 1); stageA(0, 1);
  stageB(1, 0); stageA(1, 0); stageB(1, 1);
  waitcnt_vm<VM_LEAVE>();
  __builtin_amdgcn_s_barrier();

  for (int i = 0; i < NI - 1; i++) {
    const int ta = 2 * i, tb = 2 * i + 1;
    LDB(0, 0); LDA(0, 0, 0, afrA); stageA(tb, 1);     BAR1(); MFMAS(0, 0, afrA); BAR2();
    LDA(0, 0, 1, afrB);            stageB(ta + 2, 0); BAR1(); MFMAS(0, 1, afrB); BAR2();
    LDB(0, 1); LDA(0, 1, 0, afrA); stageA(ta + 2, 0); BAR1(); MFMAS(1, 0, afrA); BAR2();
    LDA(0, 1, 1, afrB);            stageB(ta + 2, 1);
    waitcnt_vm<VM_LEAVE>();                           BAR1(); MFMAS(1, 1, afrB); BAR2();
    LDB(1, 0); LDA(1, 0, 0, afrA); stageA(ta + 2, 1); BAR1(); MFMAS(0, 0, afrA); BAR2();
    LDA(1, 0, 1, afrB);            stageB(tb + 2, 0); BAR1(); MFMAS(0, 1, afrB); BAR2();
    LDB(1, 1); LDA(1, 1, 0, afrA); stageA(tb + 2, 0); BAR1(); MFMAS(1, 0, afrA); BAR2();
    LDA(1, 1, 1, afrB);            stageB(tb + 2, 1);
    waitcnt_vm<VM_LEAVE>();                           BAR1(); MFMAS(1, 1, afrB); BAR2();
  }
  {  // tail iteration: tiles nt-2 (dbuf0), nt-1 (dbuf1); no further staging
    const int tb = nt - 1;
    LDB(0, 0); LDA(0, 0, 0, afrA); stageA(tb, 1); BAR1(); MFMAS(0, 0, afrA); BAR2();
    LDA(0, 0, 1, afrB);                           BAR1(); MFMAS(0, 1, afrB); BAR2();
    LDB(0, 1); LDA(0, 1, 0, afrA);                BAR1(); MFMAS(1, 0, afrA); BAR2();
    LDA(0, 1, 1, afrB); waitcnt_vm<0>();          BAR1(); MFMAS(1, 1, afrB); BAR2();
    LDB(1, 0); LDA(1, 0, 0, afrA);                BAR1(); MFMAS(0, 0, afrA); BAR2();
    LDA(1, 0, 1, afrB);                           BAR1(); MFMAS(0, 1, afrB); BAR2();
    LDB(1, 1); LDA(1, 1, 0, afrA);                BAR1(); MFMAS(1, 0, afrA); BAR2();
    LDA(1, 1, 1, afrB);                           BAR1(); MFMAS(1, 1, afrB); BAR2();
  }
#undef LDB
#undef LDA
#undef MFMAS
#undef BAR1
#undef BAR2

  // epilogue: D row = (lane>>4)*4 + j, col = lane&15 (m89-verified)
  const int cr0 = tm * BM + wr * (M_REP * 16) + (lane >> 4) * 4;
  const int cc0 = tn * BN + wc * 64 + (lane & 15);
#pragma unroll
  for (int m = 0; m < M_REP; m++)
#pragma unroll
    for (int n = 0; n < 4; n++)
#pragma unroll
      for (int j = 0; j < 4; j++) {
        long row = cr0 + m * 16 + j;
        long col = cc0 + n * 16;
        if (OUT_BF16)
          ((bf16*)C)[row * (long)N + col] = __float2bfloat16(acc[m][n][j]);
        else
          ((float*)C)[row * (long)N + col] = acc[m][n][j];
      }
}

// ---------------------------------------------------------------------------
// fused fp32 -> bf16 convert for x, Wq, Wk, Wv (one dispatch)
// blocks: [0,8192) x ; [8192,9216) Wq ; [9216,10240) Wk ; [10240,11264) Wv
// ---------------------------------------------------------------------------
__global__ __launch_bounds__(256) void cvt_all(const float* __restrict__ x,
                                               const float* __restrict__ wq,
                                               const float* __restrict__ wk,
                                               const float* __restrict__ wv,
                                               bf16* __restrict__ xb,
                                               bf16* __restrict__ wb) {
  const int b = blockIdx.x;
  const float* src;
  bf16* dst;
  int i;
  if (b < 8192) { src = x; dst = xb; i = b * 256 + threadIdx.x; }
  else if (b < 9216) { src = wq; dst = wb; i = (b - 8192) * 256 + threadIdx.x; }
  else if (b < 10240) { src = wk; dst = wb + 1048576; i = (b - 9216) * 256 + threadIdx.x; }
  else { src = wv; dst = wb + 2097152; i = (b - 10240) * 256 + threadIdx.x; }
  float4 f = ((const float4*)src)[i];
  union { bf16 h[4]; uint2 u; } o;
  o.h[0] = __float2bfloat16(f.x);
  o.h[1] = __float2bfloat16(f.y);
  o.h[2] = __float2bfloat16(f.z);
  o.h[3] = __float2bfloat16(f.w);
  ((uint2*)dst)[i] = o.u;
}

// ---------------------------------------------------------------------------
// causal row softmax: P[b,i,j] = softmax_j<=i( S[b,i,j]/32 ), 0 for j>i (bf16)
// one 256-thread block per row; float4 loads, uint2 packed bf16 stores
// ---------------------------------------------------------------------------
__global__ __launch_bounds__(256) void softmax_causal(const float* __restrict__ Sc,
                                                      bf16* __restrict__ P) {
  const int i = blockIdx.x, b = blockIdx.y;
  const long base = ((long)b * 2048 + i) * 2048;
  const float4* row4 = (const float4*)(Sc + base);
  bf16* prow = P + base;
  const int tid = threadIdx.x, lane = tid & 63, wv = tid >> 6;
  const int len = i + 1;

  float v[8];
  float m = -3.3e38f;
#pragma unroll
  for (int u = 0; u < 2; u++) {
    float4 f = row4[tid + u * 256];
    int j0 = (tid + u * 256) * 4;
    float* pv = v + u * 4;
    pv[0] = f.x; pv[1] = f.y; pv[2] = f.z; pv[3] = f.w;
#pragma unroll
    for (int e = 0; e < 4; e++) {
      if (j0 + e >= len) pv[e] = -3.3e38f;
      m = fmaxf(m, pv[e]);
    }
  }
  for (int o = 32; o; o >>= 1) m = fmaxf(m, __shfl_xor(m, o));
  __shared__ float redm[4], reds[4];
  if (lane == 0) redm[wv] = m;
  __syncthreads();
  m = fmaxf(fmaxf(redm[0], redm[1]), fmaxf(redm[2], redm[3]));

  const float scale = 0.03125f;  // 1/sqrt(1024)
  float e8[8];
  float s = 0.f;
#pragma unroll
  for (int u = 0; u < 2; u++) {
    int j0 = (tid + u * 256) * 4;
#pragma unroll
    for (int e = 0; e < 4; e++) {
      float t = (j0 + e < len) ? __expf((v[u * 4 + e] - m) * scale) : 0.f;
      e8[u * 4 + e] = t;
      s += t;
    }
  }
  for (int o = 32; o; o >>= 1) s += __shfl_xor(s, o);
  if (lane == 0) reds[wv] = s;
  __syncthreads();
  s = reds[0] + reds[1] + reds[2] + reds[3];
  const float inv = 1.0f / s;
#pragma unroll
  for (int u = 0; u < 2; u++) {
    int j0 = (tid + u * 256) * 4;
    union { bf16 h[4]; uint2 u2; } o;
#pragma unroll
    for (int e = 0; e < 4; e++) o.h[e] = __float2bfloat16(e8[u * 4 + e] * inv);
    *(uint2*)(prow + j0) = o.u2;
  }
}

// ---------------------------------------------------------------------------
// V[b,s,d] -> Vt[b,d,s] (bf16), 32x32 LDS tiles
// ---------------------------------------------------------------------------
__global__ __launch_bounds__(256) void transposeV(const bf16* __restrict__ V,
                                                  bf16* __restrict__ Vt) {
  __shared__ bf16 t[32][33];
  const int b = blockIdx.z;
  const int s0 = blockIdx.x << 5;
  const int d0 = blockIdx.y << 5;
  const bf16* Vb = V + (long)b * 2048 * 1024;
  bf16* Vtb = Vt + (long)b * 1024 * 2048;
  const int lx = threadIdx.x & 31, ly = threadIdx.x >> 5;
#pragma unroll
  for (int r = 0; r < 32; r += 8)
    t[r + ly][lx] = Vb[(long)(s0 + r + ly) * 1024 + d0 + lx];
  __syncthreads();
#pragma unroll
  for (int r = 0; r < 32; r += 8)
    Vtb[(long)(d0 + r + ly) * 2048 + s0 + lx] = t[lx][r + ly];
}

// ---------------------------------------------------------------------------
// Workspace (160 MB): [0,16M) Q | [16,32) K | [32,48) V | [48,64) Vt |
// [64,96) P | [96,160) Sc fp32  (aliases xb@96M + Wb@112M, dead after QKV)
// ---------------------------------------------------------------------------
extern "C" void kernel_launch(void* const* d_in, const int* in_sizes, int n_in,
                              void* d_out, int out_size, void* d_ws, size_t ws_size,
                              hipStream_t stream) {
  const float* x = (const float*)d_in[0];
  const float* Wq = (const float*)d_in[1];
  const float* Wk = (const float*)d_in[2];
  const float* Wv = (const float*)d_in[3];

  const long MBy = 1 << 20;
  char* ws = (char*)d_ws;
  bf16* Q = (bf16*)(ws);
  bf16* Kb = (bf16*)(ws + 16 * MBy);
  bf16* V = (bf16*)(ws + 32 * MBy);
  bf16* Vt = (bf16*)(ws + 48 * MBy);
  bf16* P = (bf16*)(ws + 64 * MBy);
  float* Sc = (float*)(ws + 96 * MBy);
  bf16* xb = (bf16*)(ws + 96 * MBy);
  bf16* Wb = (bf16*)(ws + 112 * MBy);

  // 1) convert inputs to bf16 (single dispatch)
  cvt_all<<<11264, 256, 0, stream>>>(x, Wq, Wk, Wv, xb, Wb);

  // 2) QKV: [8192,1024] = xb * W^T, z over {q,k,v}. 256x256 tiles, 384 blocks.
  gemm8p<8, true, false, false><<<dim3(4, 32, 3), 512, 0, stream>>>(
      xb, Wb, Q, 8192, 1024, 1024, 0L, 1048576L, 16 * MBy);

  // 3) V transpose for NT PV GEMM
  transposeV<<<dim3(64, 32, 4), 256, 0, stream>>>(V, Vt);

  // 4) scores: per batch S = Q*K^T (fp32), skip masked tiles. 144 live blocks.
  gemm8p<8, false, true, false><<<dim3(8, 8, 4), 512, 0, stream>>>(
      Q, Kb, Sc, 2048, 2048, 1024, 2048L * 1024, 2048L * 1024, 2048L * 2048 * 4);

  // 5) causal softmax (applies 1/32 scale), P bf16 with zeros above diagonal
  softmax_causal<<<dim3(2048, 4), 256, 0, stream>>>(Sc, P);

  // 6) out = P * Vt^T, causal K-limit. BM=128 halves the straggler block.
  gemm8p<4, false, false, true><<<dim3(4, 16, 4), 512, 0, stream>>>(
      P, Vt, d_out, 2048, 1024, 2048, 2048L * 2048, 1024L * 2048, 2048L * 1024 * 4);
}